// Round 2
// baseline (746.160 us; speedup 1.0000x reference)
//
#include <hip/hip_runtime.h>

// Fused AttentionAggregator: B=4096, N=64, F=128, H=8, D=64, HD=512.
// out[b,n,c] = relu(lin[b,n,c] * softmax_n(leakyrelu(att))[b, c/64, n])
// lin = x @ W_lin via fp16 MFMA (operand-swapped: A=W cols, B=x rows).
// lin stays register-resident: att partials computed by feeding the phase-B
// accumulator (C-layout) directly as the B-operand of mfma_f32_16x16x16_f16.
//
// R2: NO x staging. x[b] is 32 KB -> L1/L2-resident; each wave loads its
// B-fragments directly from global as fp32 (2x dwordx4, cache-hit after
// first touch) and converts to f16 inline -- bit-identical to the old
// cvt->LDS path. Removes phase A, the post-stage barrier AND the post-GEMM
// barrier (attbuf no longer aliases xs): 2 barriers per block, LDS 39168 B.
// (R1 post-mortem: register-parked async stage spilled under the 128-VGPR
// cap -- this kernel has no spare VGPRs; hide latency by deleting it.)

typedef _Float16 half8  __attribute__((ext_vector_type(8)));
typedef _Float16 half4v __attribute__((ext_vector_type(4)));
typedef float    f32x4  __attribute__((ext_vector_type(4)));

static constexpr int NSEQ  = 64;
static constexpr int FIN   = 128;
static constexpr int HDIM  = 512;   // H*D
static constexpr int NHEAD = 8;

// smem map (byte offsets):
//   [0, 32768)        attbuf: [w][n][j] f32 8x64x16  (phase D -> reduction)
//   [0, 34816)        ftile: per-wave [16][68] f32 x 8 (phase F, private slices;
//                     attbuf dead by then)
//   [34816, 39168)    att_s: [n][j] f32 64x17        (reduction -> E)
static constexpr int ATT_OFF    = 34816;
static constexpr int SMEM_BYTES = 39168;

// Prep: W_lin (fp32 [128][512]) -> W_linT fp16 [512][128] (k-contiguous);
//       W_att (fp32 [1024][8])  -> waA fp16 [8192]: A-fragment-ordered Wa_cat.
//       Wa_cat[c][j]: j in [0,8)  = W_att[512+c][j]   (lin term)
//                     j in [8,16) = W_att[c][j-8]     (src term)
__global__ __launch_bounds__(256) void prep_kernel(const float* __restrict__ wlin,
                                                   const float* __restrict__ watt,
                                                   _Float16* __restrict__ wlinT,
                                                   _Float16* __restrict__ waA)
{
    int t = blockIdx.x * 256 + threadIdx.x;
    if (t < HDIM * FIN) {
        int c = t >> 7;
        int k = t & 127;
        wlinT[t] = (_Float16)wlin[k * HDIM + c];
    }
    if (t < 16 * HDIM) {                 // 8192 waA halves
        int i     = t & 3;
        int lane  = (t >> 2) & 63;
        int slice = t >> 8;              // w*4 + mt, 0..31
        int c = (slice >> 2) * 64 + (slice & 3) * 16 + (lane >> 4) * 4 + i;
        int j = lane & 15;
        float v = (j < NHEAD) ? watt[(HDIM + c) * NHEAD + j]
                              : watt[c * NHEAD + (j - NHEAD)];
        waA[t] = (_Float16)v;
    }
}

__global__ __launch_bounds__(512, 4) void fused_kernel(const float* __restrict__ x,
                                                       const _Float16* __restrict__ wlinT,
                                                       const _Float16* __restrict__ waA,
                                                       const int* __restrict__ mask,
                                                       float* __restrict__ out)
{
    __shared__ char smem[SMEM_BYTES] __attribute__((aligned(16)));
    float* attbuf = (float*)smem;
    float* att_s  = (float*)(smem + ATT_OFF);

    const int b    = blockIdx.x;
    const int t    = threadIdx.x;
    const int lane = t & 63;
    const int w    = t >> 6;       // wave 0..7 == head
    const int l15  = lane & 15;
    const int quad = lane >> 4;    // 0..3

    const int mv = mask[b * NSEQ + lane];   // prefetch for phase E

    // ---- Phase B: lin^T GEMM, x read straight from global (L1/L2-resident).
    //      A = W_linT cols (m), B = x rows (n), cvt fp32->fp16 inline.
    //      acc[mt][nt] reg i: lin[n = nt*16+l15][c = 64w + mt*16 + quad*4 + i]
    f32x4 acc[4][4];
    #pragma unroll
    for (int mt = 0; mt < 4; ++mt)
        #pragma unroll
        for (int nt = 0; nt < 4; ++nt)
            acc[mt][nt] = (f32x4){0.f, 0.f, 0.f, 0.f};

    const float* xb = x + (size_t)b * (NSEQ * FIN);
    const int colbase = w * 64;
    #pragma unroll
    for (int ks = 0; ks < 4; ++ks) {
        const int k0 = ks * 32 + quad * 8;
        half8 a[4];
        #pragma unroll
        for (int mt = 0; mt < 4; ++mt)
            a[mt] = *(const half8*)(wlinT + (colbase + mt * 16 + l15) * FIN + k0);
        #pragma unroll
        for (int nt = 0; nt < 4; ++nt) {
            const float* xr = xb + (nt * 16 + l15) * FIN + k0;
            f32x4 v0 = *(const f32x4*)(xr);
            f32x4 v1 = *(const f32x4*)(xr + 4);
            half8 bfr;
            bfr[0] = (_Float16)v0[0]; bfr[1] = (_Float16)v0[1];
            bfr[2] = (_Float16)v0[2]; bfr[3] = (_Float16)v0[3];
            bfr[4] = (_Float16)v1[0]; bfr[5] = (_Float16)v1[1];
            bfr[6] = (_Float16)v1[2]; bfr[7] = (_Float16)v1[3];
            #pragma unroll
            for (int mt = 0; mt < 4; ++mt)
                acc[mt][nt] = __builtin_amdgcn_mfma_f32_16x16x32_f16(a[mt], bfr, acc[mt][nt], 0, 0, 0);
        }
    }

    // ---- Phase D: att partials T[j][n] = sum_c Wa_cat[c][j] * lin[n][c]
    //      over this wave's 64 cols, via 16x16x16 MFMA with B = cvt_f16(acc).
    {
        f32x4 T[4];
        #pragma unroll
        for (int nt = 0; nt < 4; ++nt) T[nt] = (f32x4){0.f, 0.f, 0.f, 0.f};
        #pragma unroll
        for (int mt = 0; mt < 4; ++mt) {
            half4v aF = *(const half4v*)(waA + ((w * 4 + mt) * 64 + lane) * 4);
            #pragma unroll
            for (int nt = 0; nt < 4; ++nt) {
                half4v bF;
                #pragma unroll
                for (int i = 0; i < 4; ++i) bF[i] = (_Float16)acc[mt][nt][i];
                T[nt] = __builtin_amdgcn_mfma_f32_16x16x16f16(aF, bF, T[nt], 0, 0, 0);
            }
        }
        // T[nt] C-layout: row j = quad*4+reg, col n = nt*16+l15 -> attbuf[w][n][j]
        #pragma unroll
        for (int nt = 0; nt < 4; ++nt)
            *(f32x4*)(attbuf + (w * 64 + nt * 16 + l15) * 16 + quad * 4) = T[nt];
    }
    __syncthreads();   // (1) attbuf complete

    // ---- Reduction: att[n][j] = sum_w attbuf[w][n][j] -> att_s [n][17] ----
    {
        int n  = t >> 3;          // 0..63
        int j0 = (t & 7) * 2;     // 0,2,..,14
        float s0 = 0.f, s1 = 0.f;
        #pragma unroll
        for (int ww = 0; ww < 8; ++ww) {
            const float* p = attbuf + (ww * 64 + n) * 16 + j0;
            s0 += p[0]; s1 += p[1];
        }
        att_s[n * 17 + j0]     = s0;
        att_s[n * 17 + j0 + 1] = s1;
    }
    __syncthreads();   // (2) att_s complete; attbuf dead

    // ---- Phase E: leakyrelu + mask + softmax over n; wave w -> head w; lane = n ----
    float aw_reg;
    {
        const float pen = (mv == 0) ? -1e9f : 0.0f;
        float a = att_s[lane * 17 + w] + att_s[8 + w];   // lin term + src term (n=0 row)
        a = (a >= 0.0f) ? a : 0.2f * a;                  // leakyrelu BEFORE mask
        a += pen;
        float mx = a;
        #pragma unroll
        for (int off = 32; off > 0; off >>= 1)
            mx = fmaxf(mx, __shfl_xor(mx, off, 64));
        float e = __expf(a - mx);
        float s = e;
        #pragma unroll
        for (int off = 32; off > 0; off >>= 1)
            s += __shfl_xor(s, off, 64);
        aw_reg = e / s;                                  // aw[w][lane]
    }
    // no barrier: ftile aliases attbuf (dead since reduction barrier),
    // att_s region untouched by phase F, ftile slices are wave-private.

    // ---- Phase F: out = relu(lin * aw) from registers, LDS-tile transpose
    //      for coalesced 256 B row segments. Barrier-free.
    {
        float* ft = (float*)smem + w * (16 * 68);        // private 4352 B tile
        float* outb = out + (size_t)b * (NSEQ * HDIM);
        #pragma unroll
        for (int nt = 0; nt < 4; ++nt) {
            float awv = __shfl(aw_reg, nt * 16 + l15, 64);   // aw[w][n], n = nt*16+l15
            #pragma unroll
            for (int mt = 0; mt < 4; ++mt) {
                f32x4 o;
                #pragma unroll
                for (int i = 0; i < 4; ++i)
                    o[i] = fmaxf(acc[mt][nt][i] * awv, 0.0f);
                *(f32x4*)(ft + l15 * 68 + mt * 16 + quad * 4) = o;   // [n_local][c_local]
            }
            #pragma unroll
            for (int s = 0; s < 4; ++s) {
                int r = s * 4 + quad;                    // n_local
                f32x4 v = *(const f32x4*)(ft + r * 68 + l15 * 4);
                int n = nt * 16 + r;
                __builtin_nontemporal_store(v, (f32x4*)(outb + n * HDIM + w * 64 + l15 * 4));
            }
        }
    }
}

extern "C" void kernel_launch(void* const* d_in, const int* in_sizes, int n_in,
                              void* d_out, int out_size, void* d_ws, size_t ws_size,
                              hipStream_t stream)
{
    const float* x    = (const float*)d_in[0];
    const float* wlin = (const float*)d_in[1];
    const float* watt = (const float*)d_in[2];
    const int*   mask = (const int*)d_in[3];
    float* out = (float*)d_out;

    _Float16* wlinT = (_Float16*)d_ws;             // 65536 halves = 128 KiB
    _Float16* waA   = wlinT + HDIM * FIN;          // 8192 halves = 16 KiB

    const int B = in_sizes[0] / (NSEQ * FIN);      // 4096

    prep_kernel<<<256, 256, 0, stream>>>(wlin, watt, wlinT, waA);
    fused_kernel<<<B, 512, 0, stream>>>(x, wlinT, waA, mask, out);
}

// Round 3
// 701.381 us; speedup vs baseline: 1.0638x; 1.0638x over previous
//
#include <hip/hip_runtime.h>

// Fused AttentionAggregator: B=4096, N=64, F=128, H=8, D=64, HD=512.
// out[b,n,c] = relu(lin[b,n,c] * softmax_n(leakyrelu(att))[b, c/64, n])
// lin = x @ W_lin via fp16 MFMA (operand-swapped: A=W cols, B=x rows).
// lin stays register-resident: att partials computed by feeding the phase-B
// accumulator (C-layout) directly as the B-operand of mfma_f32_16x16x16_f16.
//
// R3 = r0 structure (per-batch blocks, LDS-staged x -- R1/R2 proved both
// persistence and direct-global x reads regress) + three surgical fixes:
//   1. attbuf de-aliased from xs -> post-GEMM barrier deleted (3 barriers).
//   2. attbuf row stride 16->20 words: kills the 8-way bank conflict on
//      phase-D f32x4 writes and the 4-way on reduction reads (G4).
//   3. phase F stores acc directly (reg i = 4 consecutive c for fixed n):
//      16 aligned 64-B-line stores/lane; ftile LDS round-trip deleted.

typedef _Float16 half8  __attribute__((ext_vector_type(8)));
typedef _Float16 half4v __attribute__((ext_vector_type(4)));
typedef float    f32x4  __attribute__((ext_vector_type(4)));

static constexpr int NSEQ  = 64;
static constexpr int FIN   = 128;
static constexpr int HDIM  = 512;   // H*D
static constexpr int NHEAD = 8;
static constexpr int XS_LD = 136;   // halves; 272 B/row, b128-aligned, even bank spread
static constexpr int AB_LD = 20;    // attbuf row stride in words (16 data + 4 pad)

// smem map (byte offsets):
//   [0, 17408)        xs: x[b] fp16 [64][136]            (phases A,B)
//   [17408, 58368)    attbuf: [w][n] rows f32, stride 20 (phase D -> reduction)
//   [58368, 62720)    att_s: [n][j] f32 64x17            (reduction -> E)
static constexpr int AB_OFF     = 17408;
static constexpr int ATT_OFF    = 58368;
static constexpr int SMEM_BYTES = 62720;

// Prep: W_lin (fp32 [128][512]) -> W_linT fp16 [512][128] (k-contiguous);
//       W_att (fp32 [1024][8])  -> waA fp16 [8192]: A-fragment-ordered Wa_cat.
//       Wa_cat[c][j]: j in [0,8)  = W_att[512+c][j]   (lin term)
//                     j in [8,16) = W_att[c][j-8]     (src term)
__global__ __launch_bounds__(256) void prep_kernel(const float* __restrict__ wlin,
                                                   const float* __restrict__ watt,
                                                   _Float16* __restrict__ wlinT,
                                                   _Float16* __restrict__ waA)
{
    int t = blockIdx.x * 256 + threadIdx.x;
    if (t < HDIM * FIN) {
        int c = t >> 7;
        int k = t & 127;
        wlinT[t] = (_Float16)wlin[k * HDIM + c];
    }
    if (t < 16 * HDIM) {                 // 8192 waA halves
        int i     = t & 3;
        int lane  = (t >> 2) & 63;
        int slice = t >> 8;              // w*4 + mt, 0..31
        int c = (slice >> 2) * 64 + (slice & 3) * 16 + (lane >> 4) * 4 + i;
        int j = lane & 15;
        float v = (j < NHEAD) ? watt[(HDIM + c) * NHEAD + j]
                              : watt[c * NHEAD + (j - NHEAD)];
        waA[t] = (_Float16)v;
    }
}

__global__ __launch_bounds__(512, 4) void fused_kernel(const float* __restrict__ x,
                                                       const _Float16* __restrict__ wlinT,
                                                       const _Float16* __restrict__ waA,
                                                       const int* __restrict__ mask,
                                                       float* __restrict__ out)
{
    __shared__ char smem[SMEM_BYTES] __attribute__((aligned(16)));
    _Float16* xs     = (_Float16*)smem;
    float*    attbuf = (float*)(smem + AB_OFF);
    float*    att_s  = (float*)(smem + ATT_OFF);

    const int b    = blockIdx.x;
    const int t    = threadIdx.x;
    const int lane = t & 63;
    const int w    = t >> 6;       // wave 0..7 == head
    const int l15  = lane & 15;
    const int quad = lane >> 4;    // 0..3

    const int mv = mask[b * NSEQ + lane];   // prefetch for phase E

    // ---- Phase A: stage x[b] (fp32 64x128) -> xs fp16 [64][136] ----
    const f32x4* xb = (const f32x4*)(x + (size_t)b * (NSEQ * FIN));
    #pragma unroll
    for (int it = 0; it < 4; ++it) {
        int i = it * 512 + t;                  // float4 index, 2048 total
        f32x4 v = __builtin_nontemporal_load(&xb[i]);
        int n = i >> 5;
        int k = (i & 31) << 2;
        half4v hv;
        hv[0] = (_Float16)v[0]; hv[1] = (_Float16)v[1];
        hv[2] = (_Float16)v[2]; hv[3] = (_Float16)v[3];
        *(half4v*)(xs + n * XS_LD + k) = hv;
    }
    __syncthreads();   // (1) xs ready

    // ---- Phase B: lin^T GEMM. A = W_linT cols (m), B = x rows (n).
    //      acc[mt][nt] reg i: lin[n = nt*16+l15][c = 64w + mt*16 + quad*4 + i]
    f32x4 acc[4][4];
    #pragma unroll
    for (int mt = 0; mt < 4; ++mt)
        #pragma unroll
        for (int nt = 0; nt < 4; ++nt)
            acc[mt][nt] = (f32x4){0.f, 0.f, 0.f, 0.f};

    const int colbase = w * 64;
    #pragma unroll
    for (int ks = 0; ks < 4; ++ks) {
        const int k0 = ks * 32 + quad * 8;
        half8 a[4];
        #pragma unroll
        for (int mt = 0; mt < 4; ++mt)
            a[mt] = *(const half8*)(wlinT + (colbase + mt * 16 + l15) * FIN + k0);
        #pragma unroll
        for (int nt = 0; nt < 4; ++nt) {
            half8 bfr = *(const half8*)(xs + (nt * 16 + l15) * XS_LD + k0);
            #pragma unroll
            for (int mt = 0; mt < 4; ++mt)
                acc[mt][nt] = __builtin_amdgcn_mfma_f32_16x16x32_f16(a[mt], bfr, acc[mt][nt], 0, 0, 0);
        }
    }
    // no barrier: attbuf no longer aliases xs.

    // ---- Phase D: att partials T[j][n] = sum_c Wa_cat[c][j] * lin[n][c]
    //      over this wave's 64 cols, via 16x16x16 MFMA with B = cvt_f16(acc).
    {
        f32x4 T[4];
        #pragma unroll
        for (int nt = 0; nt < 4; ++nt) T[nt] = (f32x4){0.f, 0.f, 0.f, 0.f};
        #pragma unroll
        for (int mt = 0; mt < 4; ++mt) {
            half4v aF = *(const half4v*)(waA + ((w * 4 + mt) * 64 + lane) * 4);
            #pragma unroll
            for (int nt = 0; nt < 4; ++nt) {
                half4v bF;
                #pragma unroll
                for (int i = 0; i < 4; ++i) bF[i] = (_Float16)acc[mt][nt][i];
                T[nt] = __builtin_amdgcn_mfma_f32_16x16x16f16(aF, bF, T[nt], 0, 0, 0);
            }
        }
        // T[nt] C-layout: row j = quad*4+reg, col n = nt*16+l15 -> attbuf[w][n][j]
        #pragma unroll
        for (int nt = 0; nt < 4; ++nt)
            *(f32x4*)(attbuf + (w * 64 + nt * 16 + l15) * AB_LD + quad * 4) = T[nt];
    }
    __syncthreads();   // (2) attbuf complete

    // ---- Reduction: att[n][j] = sum_w attbuf[w][n][j] -> att_s [n][17] ----
    {
        int n  = t >> 3;          // 0..63
        int j0 = (t & 7) * 2;     // 0,2,..,14
        float s0 = 0.f, s1 = 0.f;
        #pragma unroll
        for (int ww = 0; ww < 8; ++ww) {
            const float* p = attbuf + (ww * 64 + n) * AB_LD + j0;
            s0 += p[0]; s1 += p[1];
        }
        att_s[n * 17 + j0]     = s0;
        att_s[n * 17 + j0 + 1] = s1;
    }
    __syncthreads();   // (3) att_s complete

    // ---- Phase E: leakyrelu + mask + softmax over n; wave w -> head w; lane = n ----
    float aw_reg;
    {
        const float pen = (mv == 0) ? -1e9f : 0.0f;
        float a = att_s[lane * 17 + w] + att_s[8 + w];   // lin term + src term (n=0 row)
        a = (a >= 0.0f) ? a : 0.2f * a;                  // leakyrelu BEFORE mask
        a += pen;
        float mx = a;
        #pragma unroll
        for (int off = 32; off > 0; off >>= 1)
            mx = fmaxf(mx, __shfl_xor(mx, off, 64));
        float e = __expf(a - mx);
        float s = e;
        #pragma unroll
        for (int off = 32; off > 0; off >>= 1)
            s += __shfl_xor(s, off, 64);
        aw_reg = e / s;                                  // aw[w][lane]
    }

    // ---- Phase F: out = relu(lin * aw) stored DIRECTLY from registers.
    //      acc[mt][nt] reg i = lin[n][64w + mt*16 + quad*4 + i]: 4 consecutive
    //      c per lane -> f32x4 store = 16 aligned 64-B cache lines per instr.
    //      No LDS, no barrier.
    {
        float* outb = out + (size_t)b * (NSEQ * HDIM);
        #pragma unroll
        for (int nt = 0; nt < 4; ++nt) {
            float awv = __shfl(aw_reg, nt * 16 + l15, 64);   // aw[w][n], n = nt*16+l15
            float* orow = outb + (nt * 16 + l15) * HDIM + w * 64 + quad * 4;
            #pragma unroll
            for (int mt = 0; mt < 4; ++mt) {
                f32x4 o;
                #pragma unroll
                for (int i = 0; i < 4; ++i)
                    o[i] = fmaxf(acc[mt][nt][i] * awv, 0.0f);
                __builtin_nontemporal_store(o, (f32x4*)(orow + mt * 16));
            }
        }
    }
}

extern "C" void kernel_launch(void* const* d_in, const int* in_sizes, int n_in,
                              void* d_out, int out_size, void* d_ws, size_t ws_size,
                              hipStream_t stream)
{
    const float* x    = (const float*)d_in[0];
    const float* wlin = (const float*)d_in[1];
    const float* watt = (const float*)d_in[2];
    const int*   mask = (const int*)d_in[3];
    float* out = (float*)d_out;

    _Float16* wlinT = (_Float16*)d_ws;             // 65536 halves = 128 KiB
    _Float16* waA   = wlinT + HDIM * FIN;          // 8192 halves = 16 KiB

    const int B = in_sizes[0] / (NSEQ * FIN);      // 4096

    prep_kernel<<<256, 256, 0, stream>>>(wlin, watt, wlinT, waA);
    fused_kernel<<<B, 512, 0, stream>>>(x, wlinT, waA, mask, out);
}

// Round 5
// 639.091 us; speedup vs baseline: 1.1675x; 1.0975x over previous
//
#include <hip/hip_runtime.h>

// Fused AttentionAggregator: B=4096, N=64, F=128, H=8, D=64, HD=512.
// out[b,n,c] = relu(lin[b,n,c] * softmax_n(leakyrelu(att))[b, c/64, n])
// lin = x @ W_lin via fp16 MFMA (operand-swapped: A=W cols, B=x rows).
// lin stays register-resident: att partials computed by feeding the phase-B
// accumulator (C-layout) directly as the B-operand of mfma_f32_16x16x16_f16.
//
// R5 = R4 resubmitted verbatim (R4 bench was an infra failure, no data):
//   1. attbuf de-aliased from xs -> post-GEMM barrier deleted (3 barriers).
//   2. attbuf row stride 20 words (pad).
//   3. phase F via ftile LDS transpose: 256-B contiguous row segments ->
//      FULL 128-B-line NT stores. (R3's direct 64-B row chunks were
//      half-line writes -> L2 read-modify-write, +~537 MB fetch, +63us.)

typedef _Float16 half8  __attribute__((ext_vector_type(8)));
typedef _Float16 half4v __attribute__((ext_vector_type(4)));
typedef float    f32x4  __attribute__((ext_vector_type(4)));

static constexpr int NSEQ  = 64;
static constexpr int FIN   = 128;
static constexpr int HDIM  = 512;   // H*D
static constexpr int NHEAD = 8;
static constexpr int XS_LD = 136;   // halves; 272 B/row, b128-aligned, even bank spread
static constexpr int AB_LD = 20;    // attbuf row stride in words (16 data + 4 pad)

// smem map (byte offsets):
//   [0, 17408)        xs: x[b] fp16 [64][136]            (phases A,B)
//   [17408, 58368)    attbuf: [w][n] rows f32, stride 20 (phase D -> reduction)
//                     ftile aliases this region in phase F (attbuf dead):
//                     per-wave [16][68] f32 x 8 = 34816 B
//   [58368, 62720)    att_s: [n][j] f32 64x17            (reduction -> E)
static constexpr int AB_OFF     = 17408;
static constexpr int ATT_OFF    = 58368;
static constexpr int SMEM_BYTES = 62720;

// Prep: W_lin (fp32 [128][512]) -> W_linT fp16 [512][128] (k-contiguous);
//       W_att (fp32 [1024][8])  -> waA fp16 [8192]: A-fragment-ordered Wa_cat.
//       Wa_cat[c][j]: j in [0,8)  = W_att[512+c][j]   (lin term)
//                     j in [8,16) = W_att[c][j-8]     (src term)
__global__ __launch_bounds__(256) void prep_kernel(const float* __restrict__ wlin,
                                                   const float* __restrict__ watt,
                                                   _Float16* __restrict__ wlinT,
                                                   _Float16* __restrict__ waA)
{
    int t = blockIdx.x * 256 + threadIdx.x;
    if (t < HDIM * FIN) {
        int c = t >> 7;
        int k = t & 127;
        wlinT[t] = (_Float16)wlin[k * HDIM + c];
    }
    if (t < 16 * HDIM) {                 // 8192 waA halves
        int i     = t & 3;
        int lane  = (t >> 2) & 63;
        int slice = t >> 8;              // w*4 + mt, 0..31
        int c = (slice >> 2) * 64 + (slice & 3) * 16 + (lane >> 4) * 4 + i;
        int j = lane & 15;
        float v = (j < NHEAD) ? watt[(HDIM + c) * NHEAD + j]
                              : watt[c * NHEAD + (j - NHEAD)];
        waA[t] = (_Float16)v;
    }
}

__global__ __launch_bounds__(512, 4) void fused_kernel(const float* __restrict__ x,
                                                       const _Float16* __restrict__ wlinT,
                                                       const _Float16* __restrict__ waA,
                                                       const int* __restrict__ mask,
                                                       float* __restrict__ out)
{
    __shared__ char smem[SMEM_BYTES] __attribute__((aligned(16)));
    _Float16* xs     = (_Float16*)smem;
    float*    attbuf = (float*)(smem + AB_OFF);
    float*    att_s  = (float*)(smem + ATT_OFF);

    const int b    = blockIdx.x;
    const int t    = threadIdx.x;
    const int lane = t & 63;
    const int w    = t >> 6;       // wave 0..7 == head
    const int l15  = lane & 15;
    const int quad = lane >> 4;    // 0..3

    // ---- Phase A: stage x[b] (fp32 64x128) -> xs fp16 [64][136].
    //      Loads issued first so the cold HBM reads start at cycle ~0.
    const f32x4* xb = (const f32x4*)(x + (size_t)b * (NSEQ * FIN));
    f32x4 v0 = __builtin_nontemporal_load(&xb[t]);
    f32x4 v1 = __builtin_nontemporal_load(&xb[512 + t]);
    f32x4 v2 = __builtin_nontemporal_load(&xb[1024 + t]);
    f32x4 v3 = __builtin_nontemporal_load(&xb[1536 + t]);
    const int mv = mask[b * NSEQ + lane];   // prefetch for phase E
    {
        f32x4 vv[4] = {v0, v1, v2, v3};
        #pragma unroll
        for (int it = 0; it < 4; ++it) {
            int i = it * 512 + t;                  // float4 index, 2048 total
            int n = i >> 5;
            int k = (i & 31) << 2;
            half4v hv;
            hv[0] = (_Float16)vv[it][0]; hv[1] = (_Float16)vv[it][1];
            hv[2] = (_Float16)vv[it][2]; hv[3] = (_Float16)vv[it][3];
            *(half4v*)(xs + n * XS_LD + k) = hv;
        }
    }
    __syncthreads();   // (1) xs ready

    // ---- Phase B: lin^T GEMM. A = W_linT cols (m), B = x rows (n).
    //      acc[mt][nt] reg i: lin[n = nt*16+l15][c = 64w + mt*16 + quad*4 + i]
    f32x4 acc[4][4];
    #pragma unroll
    for (int mt = 0; mt < 4; ++mt)
        #pragma unroll
        for (int nt = 0; nt < 4; ++nt)
            acc[mt][nt] = (f32x4){0.f, 0.f, 0.f, 0.f};

    const int colbase = w * 64;
    #pragma unroll
    for (int ks = 0; ks < 4; ++ks) {
        const int k0 = ks * 32 + quad * 8;
        half8 a[4];
        #pragma unroll
        for (int mt = 0; mt < 4; ++mt)
            a[mt] = *(const half8*)(wlinT + (colbase + mt * 16 + l15) * FIN + k0);
        #pragma unroll
        for (int nt = 0; nt < 4; ++nt) {
            half8 bfr = *(const half8*)(xs + (nt * 16 + l15) * XS_LD + k0);
            #pragma unroll
            for (int mt = 0; mt < 4; ++mt)
                acc[mt][nt] = __builtin_amdgcn_mfma_f32_16x16x32_f16(a[mt], bfr, acc[mt][nt], 0, 0, 0);
        }
    }
    // no barrier: attbuf does not alias xs.

    // ---- Phase D: att partials T[j][n] = sum_c Wa_cat[c][j] * lin[n][c]
    //      over this wave's 64 cols, via 16x16x16 MFMA with B = cvt_f16(acc).
    {
        f32x4 T[4];
        #pragma unroll
        for (int nt = 0; nt < 4; ++nt) T[nt] = (f32x4){0.f, 0.f, 0.f, 0.f};
        #pragma unroll
        for (int mt = 0; mt < 4; ++mt) {
            half4v aF = *(const half4v*)(waA + ((w * 4 + mt) * 64 + lane) * 4);
            #pragma unroll
            for (int nt = 0; nt < 4; ++nt) {
                half4v bF;
                #pragma unroll
                for (int i = 0; i < 4; ++i) bF[i] = (_Float16)acc[mt][nt][i];
                T[nt] = __builtin_amdgcn_mfma_f32_16x16x16f16(aF, bF, T[nt], 0, 0, 0);
            }
        }
        // T[nt] C-layout: row j = quad*4+reg, col n = nt*16+l15 -> attbuf[w][n][j]
        #pragma unroll
        for (int nt = 0; nt < 4; ++nt)
            *(f32x4*)(attbuf + (w * 64 + nt * 16 + l15) * AB_LD + quad * 4) = T[nt];
    }
    __syncthreads();   // (2) attbuf complete

    // ---- Reduction: att[n][j] = sum_w attbuf[w][n][j] -> att_s [n][17] ----
    {
        int n  = t >> 3;          // 0..63
        int j0 = (t & 7) * 2;     // 0,2,..,14
        float s0 = 0.f, s1 = 0.f;
        #pragma unroll
        for (int ww = 0; ww < 8; ++ww) {
            const float* p = attbuf + (ww * 64 + n) * AB_LD + j0;
            s0 += p[0]; s1 += p[1];
        }
        att_s[n * 17 + j0]     = s0;
        att_s[n * 17 + j0 + 1] = s1;
    }
    __syncthreads();   // (3) att_s complete; attbuf dead

    // ---- Phase E: leakyrelu + mask + softmax over n; wave w -> head w; lane = n ----
    float aw_reg;
    {
        const float pen = (mv == 0) ? -1e9f : 0.0f;
        float a = att_s[lane * 17 + w] + att_s[8 + w];   // lin term + src term (n=0 row)
        a = (a >= 0.0f) ? a : 0.2f * a;                  // leakyrelu BEFORE mask
        a += pen;
        float mx = a;
        #pragma unroll
        for (int off = 32; off > 0; off >>= 1)
            mx = fmaxf(mx, __shfl_xor(mx, off, 64));
        float e = __expf(a - mx);
        float s = e;
        #pragma unroll
        for (int off = 32; off > 0; off >>= 1)
            s += __shfl_xor(s, off, 64);
        aw_reg = e / s;                                  // aw[w][lane]
    }
    // no barrier: ftile aliases attbuf (dead since reduction barrier),
    // att_s region untouched by phase F, ftile slices are wave-private.

    // ---- Phase F: out = relu(lin * aw) via per-wave LDS tile transpose:
    //      256-B contiguous row segments -> full 128-B-line NT stores.
    {
        float* ft = (float*)(smem + AB_OFF) + w * (16 * 68);  // private 4352 B tile
        float* outb = out + (size_t)b * (NSEQ * HDIM);
        #pragma unroll
        for (int nt = 0; nt < 4; ++nt) {
            float awv = __shfl(aw_reg, nt * 16 + l15, 64);    // aw[w][n], n = nt*16+l15
            #pragma unroll
            for (int mt = 0; mt < 4; ++mt) {
                f32x4 o;
                #pragma unroll
                for (int i = 0; i < 4; ++i)
                    o[i] = fmaxf(acc[mt][nt][i] * awv, 0.0f);
                *(f32x4*)(ft + l15 * 68 + mt * 16 + quad * 4) = o;   // [n_local][c_local]
            }
            #pragma unroll
            for (int s = 0; s < 4; ++s) {
                int r = s * 4 + quad;                    // n_local
                f32x4 v = *(const f32x4*)(ft + r * 68 + l15 * 4);
                int n = nt * 16 + r;
                __builtin_nontemporal_store(v, (f32x4*)(outb + n * HDIM + w * 64 + l15 * 4));
            }
        }
    }
}

extern "C" void kernel_launch(void* const* d_in, const int* in_sizes, int n_in,
                              void* d_out, int out_size, void* d_ws, size_t ws_size,
                              hipStream_t stream)
{
    const float* x    = (const float*)d_in[0];
    const float* wlin = (const float*)d_in[1];
    const float* watt = (const float*)d_in[2];
    const int*   mask = (const int*)d_in[3];
    float* out = (float*)d_out;

    _Float16* wlinT = (_Float16*)d_ws;             // 65536 halves = 128 KiB
    _Float16* waA   = wlinT + HDIM * FIN;          // 8192 halves = 16 KiB

    const int B = in_sizes[0] / (NSEQ * FIN);      // 4096

    prep_kernel<<<256, 256, 0, stream>>>(wlin, watt, wlinT, waA);
    fused_kernel<<<B, 512, 0, stream>>>(x, wlinT, waA, mask, out);
}